// Round 9
// baseline (658.952 us; speedup 1.0000x reference)
//
#include <hip/hip_runtime.h>

#define S_LEN 512
#define BATCH 256
#define EMB   300
#define HID   256
#define VOCAB 50257
#define NPROD 786
#define NLOG2E -1.44269504089f

#define EW_BYTES 25731584ull            // 50257*256*2 (f16, pre-scaled by -log2e)
#define KPAD 320                        // WiT k-stride (300 padded to 320)

typedef __attribute__((ext_vector_type(8))) _Float16 f16x8;
typedef __attribute__((ext_vector_type(4))) _Float16 f16x4;
typedef __attribute__((ext_vector_type(2))) __fp16   fp16v2;
typedef __attribute__((ext_vector_type(4))) float    f32x4;

// Barrier waiting only lgkmcnt(0): LDS ordered, global loads stay in flight.
__device__ __forceinline__ void block_sync_lds() {
    asm volatile("" ::: "memory");
    __builtin_amdgcn_s_waitcnt(0xC07F);   // vmcnt=63, expcnt=7, lgkmcnt=0
    __builtin_amdgcn_s_barrier();
    asm volatile("" ::: "memory");
}

__device__ __forceinline__ float sigmoid_scaled(float xs) {   // xs = -log2e * x
    float e = __builtin_amdgcn_exp2f(xs);
    return __builtin_amdgcn_rcpf(1.0f + e);
}

// ---------------------------------------------------------------------------
// WiT[n][k] = f16( Wi[k][n] * -log2e ), k padded 300->320 with zeros.
// ---------------------------------------------------------------------------
__global__ __launch_bounds__(256)
void k_wprep(const float* __restrict__ Wi, _Float16* __restrict__ WiT) {
    const int k = blockIdx.x;      // 0..319
    const int n = threadIdx.x;     // 0..255
    _Float16 v = (_Float16)0.f;
    if (k < EMB) v = (_Float16)(Wi[k * HID + n] * NLOG2E);
    WiT[n * KPAD + k] = v;
}

// ---------------------------------------------------------------------------
// Producer: unchanged from R4.
// ---------------------------------------------------------------------------
__global__ __launch_bounds__(256, 3)
void k_embwi(const float* __restrict__ emb, const _Float16* __restrict__ WiT,
             _Float16* __restrict__ EW) {
    const int tid  = threadIdx.x;
    const int wv   = tid >> 6;
    const int lane = tid & 63;
    const int ln   = lane & 15;
    const int q    = lane >> 4;
    const int m0   = blockIdx.x * 64;

    const _Float16* wbn[4];
#pragma unroll
    for (int nt = 0; nt < 4; nt++)
        wbn[nt] = WiT + (wv * 64 + nt * 16 + ln) * KPAD + q * 8;

    const float* arow[4];
#pragma unroll
    for (int mt = 0; mt < 4; mt++) {
        int row = m0 + mt * 16 + ln; if (row >= VOCAB) row = VOCAB - 1;
        arow[mt] = emb + (long)row * EMB + q * 8;
    }

    auto load_af = [&](int kc, int mt) -> f16x8 {
        const float* p = arow[mt] + kc * 32;
        f16x8 v;
        if (kc < 9 || q == 0) {
            f32x4 a = *(const f32x4*)p;
            f32x4 b = *(const f32x4*)(p + 4);
#pragma unroll
            for (int r = 0; r < 4; r++) { v[r] = (_Float16)a[r]; v[4 + r] = (_Float16)b[r]; }
        } else if (q == 1) {
            f32x4 a = *(const f32x4*)p;
#pragma unroll
            for (int r = 0; r < 4; r++) { v[r] = (_Float16)a[r]; v[4 + r] = (_Float16)0.f; }
        } else {
#pragma unroll
            for (int r = 0; r < 8; r++) v[r] = (_Float16)0.f;
        }
        return v;
    };

    f32x4 acc[4][4];
#pragma unroll
    for (int mt = 0; mt < 4; mt++)
#pragma unroll
        for (int nt = 0; nt < 4; nt++)
            acc[mt][nt] = f32x4{0.f, 0.f, 0.f, 0.f};

#pragma unroll
    for (int kc = 0; kc < 10; kc++) {
        f16x8 af[4], bf[4];
#pragma unroll
        for (int mt = 0; mt < 4; mt++) af[mt] = load_af(kc, mt);
#pragma unroll
        for (int nt = 0; nt < 4; nt++) bf[nt] = *(const f16x8*)(wbn[nt] + kc * 32);
#pragma unroll
        for (int mt = 0; mt < 4; mt++)
#pragma unroll
            for (int nt = 0; nt < 4; nt++)
                acc[mt][nt] = __builtin_amdgcn_mfma_f32_16x16x32_f16(
                    af[mt], bf[nt], acc[mt][nt], 0, 0, 0);
    }

#pragma unroll
    for (int mt = 0; mt < 4; mt++)
#pragma unroll
        for (int nt = 0; nt < 4; nt++) {
            const int col = wv * 64 + nt * 16 + ln;
#pragma unroll
            for (int r = 0; r < 4; r++) {
                const int mm = m0 + mt * 16 + q * 4 + r;
                if (mm < VOCAB) EW[(long)mm * HID + col] = (_Float16)acc[mt][nt][r];
            }
        }
}

// ---------------------------------------------------------------------------
// Consumer R9: two interleaved recurrences per block (16 rows = groups A,B).
// R5-R8 pinned step at ~1300 cyc independent of LDS volume/conflicts/waves:
// lockstep waves can't hide the serial chain (barrier->ds_read->MFMA
// chain->sigmoid->write->barrier). Fix: software phase-stagger. Per phase:
//   readB(t) issue | computeA(t) | BAR | readA(t+1) issue | computeB(t) | BAR
// Every barrier is followed by MFMAs whose hf operands were prefetched in
// the PREVIOUS half-phase -> ds_read latency + chain tail hide under the
// other group's compute. Barriers/step unchanged. Prefetched buffers are
// >=2 barriers from their next overwrite (no WAR). abuf parity unrolled
// statically (rule #20). 16 blocks x 512 thr; VGPR ~190 (2 waves/SIMD).
// ---------------------------------------------------------------------------
#define HSTR 272
#define HB8  (8 * HSTR)
#define WSTR 513

__global__ __launch_bounds__(512, 1)
void k_recur(const float* __restrict__ Wh, const _Float16* __restrict__ EW,
             const int* __restrict__ words,
             const float* __restrict__ fcw, const float* __restrict__ fcb,
             float* __restrict__ out) {
    __shared__ __attribute__((aligned(16))) _Float16 hbufA[2 * HB8];
    __shared__ __attribute__((aligned(16))) _Float16 hbufB[2 * HB8];
    __shared__ float red[512];
    __shared__ int   wlds[16 * WSTR];

    const int tid  = threadIdx.x;
    const int wv   = tid >> 6;        // 0..7, j-slice of 32
    const int lane = tid & 63;
    const int ln   = lane & 15;
    const int lnn  = ln & 7;          // broadcast source row within group
    const int q    = lane >> 4;
    const int b0   = blockIdx.x * 16;

    // Wh^T frags (scaled by -log2e): A'[m=j][k], j = wv*32 + mt*16 + ln
    f16x8 whf[8][2];
#pragma unroll
    for (int kc = 0; kc < 8; kc++) {
#pragma unroll
        for (int mt = 0; mt < 2; mt++) {
            const int j = wv * 32 + mt * 16 + ln;
            f16x8 u;
#pragma unroll
            for (int jj = 0; jj < 8; jj++)
                u[jj] = (_Float16)(Wh[(kc * 32 + q * 8 + jj) * HID + j] * NLOG2E);
            whf[kc][mt] = u;
        }
    }

    // Preload 16 word rows (coalesced) + zero both h ping-pong buffers
#pragma unroll
    for (int i = tid; i < 16 * S_LEN; i += 512) {
        const int r = i >> 9, c = i & 511;
        wlds[r * WSTR + c] = words[(b0 + r) * S_LEN + c];
    }
    for (int i = tid; i < 2 * HB8; i += 512) { hbufA[i] = (_Float16)0.f; hbufB[i] = (_Float16)0.f; }
    __syncthreads();

    const int jbase = wv * 32 + q * 4;   // + mt*16
    const int* wrA = wlds + lnn * WSTR;          // group A rows 0..7
    const int* wrB = wlds + (8 + lnn) * WSTR;    // group B rows 8..15

    f16x4 abA0[2], abA1[2], abB0[2], abB1[2];
    {
        const _Float16* pA0 = EW + ((long)wrA[0] << 8) + jbase;
        const _Float16* pA1 = EW + ((long)wrA[1] << 8) + jbase;
        const _Float16* pB0 = EW + ((long)wrB[0] << 8) + jbase;
        const _Float16* pB1 = EW + ((long)wrB[1] << 8) + jbase;
#pragma unroll
        for (int mt = 0; mt < 2; mt++) {
            abA0[mt] = *(const f16x4*)(pA0 + mt * 16);
            abA1[mt] = *(const f16x4*)(pA1 + mt * 16);
            abB0[mt] = *(const f16x4*)(pB0 + mt * 16);
            abB1[mt] = *(const f16x4*)(pB1 + mt * 16);
        }
    }

#define READH(HF, HR)                                                                   \
    _Pragma("unroll")                                                                   \
    for (int kc = 0; kc < 8; kc++)                                                      \
        HF[kc] = *(const f16x8*)((HR) + lnn * HSTR + kc * 32 + q * 8);

#define GCOMP(HF, AB, HW, WR, T)                                                        \
    {                                                                                   \
        f32x4 acc_a[2], acc_b[2];                                                       \
        _Pragma("unroll")                                                               \
        for (int mt = 0; mt < 2; mt++) {            /* preact (f16->f32) as C-init */   \
            f16x4 av = AB[mt];                                                          \
            acc_a[mt] = f32x4{(float)av[0], (float)av[1], (float)av[2], (float)av[3]};  \
            acc_b[mt] = f32x4{0.f, 0.f, 0.f, 0.f};                                      \
        }                                                                               \
        const int t2_ = ((T) + 2 > 511) ? 511 : ((T) + 2);                              \
        const _Float16* rp_ = EW + ((long)WR[t2_] << 8) + jbase;                        \
        _Pragma("unroll")                                                               \
        for (int mt = 0; mt < 2; mt++) AB[mt] = *(const f16x4*)(rp_ + mt * 16);         \
        _Pragma("unroll")                                                               \
        for (int r = 0; r < 4; r++) {               /* 4 chains, depth 4 */             \
            _Pragma("unroll")                                                           \
            for (int mt = 0; mt < 2; mt++)                                              \
                acc_a[mt] = __builtin_amdgcn_mfma_f32_16x16x32_f16(                     \
                    whf[r][mt], HF[r], acc_a[mt], 0, 0, 0);                             \
            _Pragma("unroll")                                                           \
            for (int mt = 0; mt < 2; mt++)                                              \
                acc_b[mt] = __builtin_amdgcn_mfma_f32_16x16x32_f16(                     \
                    whf[r + 4][mt], HF[r + 4], acc_b[mt], 0, 0, 0);                     \
        }                                                                               \
        _Pragma("unroll")                                                               \
        for (int mt = 0; mt < 2; mt++) {                                                \
            f32x4 s = acc_a[mt] + acc_b[mt];                                            \
            float r0 = sigmoid_scaled(s[0]), r1 = sigmoid_scaled(s[1]);                 \
            float r2 = sigmoid_scaled(s[2]), r3 = sigmoid_scaled(s[3]);                 \
            union { fp16v2 h2[2]; f16x4 v4; } hp;                                       \
            hp.h2[0] = __builtin_amdgcn_cvt_pkrtz(r0, r1);                              \
            hp.h2[1] = __builtin_amdgcn_cvt_pkrtz(r2, r3);                              \
            if (ln < 8)                                                                 \
                *(f16x4*)((HW) + ln * HSTR + wv * 32 + mt * 16 + q * 4) = hp.v4;        \
        }                                                                               \
    }

// One phase: advance A and B by one timestep T.
//   readB(T) -> computeA(T) -> BAR -> readA(T+1) -> computeB(T) -> BAR
#define PHASE(T, ABA, ABB, HRB, HWA, HWB)                                               \
    {                                                                                   \
        READH(hfB, HRB);                                                                \
        GCOMP(hfA, ABA, HWA, wrA, T);                                                   \
        block_sync_lds();                                                               \
        READH(hfA, HWA);                                                                \
        GCOMP(hfB, ABB, HWB, wrB, T);                                                   \
        block_sync_lds();                                                               \
    }

    f16x8 hfA[8], hfB[8];
    READH(hfA, hbufA);           // h0 = 0 (buffer 0 zeroed)

    for (int t = 0; t < S_LEN; t += 2) {
        // even step: reads buffer 0, writes buffer 1
        PHASE(t,     abA0, abB0, hbufB,       hbufA + HB8, hbufB + HB8);
        // odd step: reads buffer 1, writes buffer 0
        PHASE(t + 1, abA1, abB1, hbufB + HB8, hbufA,       hbufB);
    }
#undef PHASE
#undef GCOMP
#undef READH

    // step 511 (odd) wrote buffer 0 of each group
    {   // hidden -> out[256 + (b0+row)*256 + j], rows 0..15, 8 f32 per thread
        const int row = tid >> 5, j0 = (tid & 31) * 8;
        const _Float16* hsrc = (row < 8) ? (hbufA + row * HSTR)
                                         : (hbufB + (row - 8) * HSTR);
        float* dst = out + 256 + (long)(b0 + row) * HID + j0;
        f32x4 w0v, w1v;
#pragma unroll
        for (int r = 0; r < 4; r++) {
            w0v[r] = (float)hsrc[j0 + r];
            w1v[r] = (float)hsrc[j0 + 4 + r];
        }
        *(f32x4*)dst = w0v;
        *(f32x4*)(dst + 4) = w1v;
    }

    {   // sig head: 32 partials x 8 elems per row
        const int row = tid >> 5, part = tid & 31;
        const _Float16* hsrc = (row < 8) ? (hbufA + row * HSTR)
                                         : (hbufB + (row - 8) * HSTR);
        float s = 0.f;
#pragma unroll
        for (int jj = 0; jj < 8; jj++) {
            const int j = part * 8 + jj;
            s += (float)hsrc[j] * fcw[j];
        }
        red[row * 32 + part] = s;
    }
    __syncthreads();
    if (tid < 16) {
        float s = fcb[0];
#pragma unroll
        for (int p = 0; p < 32; p++) s += red[tid * 32 + p];
        s *= NLOG2E;
        out[b0 + tid] = sigmoid_scaled(s);
    }
}

extern "C" void kernel_launch(void* const* d_in, const int* in_sizes, int n_in,
                              void* d_out, int out_size, void* d_ws, size_t ws_size,
                              hipStream_t stream) {
    const int*   words = (const int*)d_in[0];
    const float* emb   = (const float*)d_in[1];
    const float* Wi    = (const float*)d_in[2];
    const float* Wh    = (const float*)d_in[3];
    const float* fcw   = (const float*)d_in[4];
    const float* fcb   = (const float*)d_in[5];
    _Float16* EW   = (_Float16*)d_ws;                          // 25.7 MB f16
    _Float16* WiT  = (_Float16*)((char*)d_ws + EW_BYTES);      // 160 KB f16
    float*    outp = (float*)d_out;

    hipLaunchKernelGGL(k_wprep, dim3(KPAD), dim3(256), 0, stream, Wi, WiT);
    hipLaunchKernelGGL(k_embwi, dim3(NPROD), dim3(256), 0, stream, emb, WiT, EW);
    hipLaunchKernelGGL(k_recur, dim3(BATCH / 16), dim3(512), 0, stream,
                       Wh, EW, words, fcw, fcb, outp);
}

// Round 10
// 439.154 us; speedup vs baseline: 1.5005x; 1.5005x over previous
//
#include <hip/hip_runtime.h>

#define S_LEN 512
#define BATCH 256
#define EMB   300
#define HID   256
#define VOCAB 50257
#define NPROD 786
#define NLOG2E -1.44269504089f

#define EW_BYTES 25731584ull            // 50257*256*2 (f16, pre-scaled by -log2e)
#define KPAD 320                        // WiT k-stride (300 padded to 320)

typedef __attribute__((ext_vector_type(8))) _Float16 f16x8;
typedef __attribute__((ext_vector_type(4))) _Float16 f16x4;
typedef __attribute__((ext_vector_type(2))) __fp16   fp16v2;
typedef __attribute__((ext_vector_type(4))) float    f32x4;

// Barrier waiting only lgkmcnt(0): LDS ordered, global loads stay in flight.
__device__ __forceinline__ void block_sync_lds() {
    asm volatile("" ::: "memory");
    __builtin_amdgcn_s_waitcnt(0xC07F);   // vmcnt=63, expcnt=7, lgkmcnt=0
    __builtin_amdgcn_s_barrier();
    asm volatile("" ::: "memory");
}

__device__ __forceinline__ float sigmoid_scaled(float xs) {   // xs = -log2e * x
    float e = __builtin_amdgcn_exp2f(xs);
    return __builtin_amdgcn_rcpf(1.0f + e);
}

// ---------------------------------------------------------------------------
// WiT[n][k] = f16( Wi[k][n] * -log2e ), k padded 300->320 with zeros.
// ---------------------------------------------------------------------------
__global__ __launch_bounds__(256)
void k_wprep(const float* __restrict__ Wi, _Float16* __restrict__ WiT) {
    const int k = blockIdx.x;      // 0..319
    const int n = threadIdx.x;     // 0..255
    _Float16 v = (_Float16)0.f;
    if (k < EMB) v = (_Float16)(Wi[k * HID + n] * NLOG2E);
    WiT[n * KPAD + k] = v;
}

// ---------------------------------------------------------------------------
// Producer: unchanged from R4.
// ---------------------------------------------------------------------------
__global__ __launch_bounds__(256, 3)
void k_embwi(const float* __restrict__ emb, const _Float16* __restrict__ WiT,
             _Float16* __restrict__ EW) {
    const int tid  = threadIdx.x;
    const int wv   = tid >> 6;
    const int lane = tid & 63;
    const int ln   = lane & 15;
    const int q    = lane >> 4;
    const int m0   = blockIdx.x * 64;

    const _Float16* wbn[4];
#pragma unroll
    for (int nt = 0; nt < 4; nt++)
        wbn[nt] = WiT + (wv * 64 + nt * 16 + ln) * KPAD + q * 8;

    const float* arow[4];
#pragma unroll
    for (int mt = 0; mt < 4; mt++) {
        int row = m0 + mt * 16 + ln; if (row >= VOCAB) row = VOCAB - 1;
        arow[mt] = emb + (long)row * EMB + q * 8;
    }

    auto load_af = [&](int kc, int mt) -> f16x8 {
        const float* p = arow[mt] + kc * 32;
        f16x8 v;
        if (kc < 9 || q == 0) {
            f32x4 a = *(const f32x4*)p;
            f32x4 b = *(const f32x4*)(p + 4);
#pragma unroll
            for (int r = 0; r < 4; r++) { v[r] = (_Float16)a[r]; v[4 + r] = (_Float16)b[r]; }
        } else if (q == 1) {
            f32x4 a = *(const f32x4*)p;
#pragma unroll
            for (int r = 0; r < 4; r++) { v[r] = (_Float16)a[r]; v[4 + r] = (_Float16)0.f; }
        } else {
#pragma unroll
            for (int r = 0; r < 8; r++) v[r] = (_Float16)0.f;
        }
        return v;
    };

    f32x4 acc[4][4];
#pragma unroll
    for (int mt = 0; mt < 4; mt++)
#pragma unroll
        for (int nt = 0; nt < 4; nt++)
            acc[mt][nt] = f32x4{0.f, 0.f, 0.f, 0.f};

#pragma unroll
    for (int kc = 0; kc < 10; kc++) {
        f16x8 af[4], bf[4];
#pragma unroll
        for (int mt = 0; mt < 4; mt++) af[mt] = load_af(kc, mt);
#pragma unroll
        for (int nt = 0; nt < 4; nt++) bf[nt] = *(const f16x8*)(wbn[nt] + kc * 32);
#pragma unroll
        for (int mt = 0; mt < 4; mt++)
#pragma unroll
            for (int nt = 0; nt < 4; nt++)
                acc[mt][nt] = __builtin_amdgcn_mfma_f32_16x16x32_f16(
                    af[mt], bf[nt], acc[mt][nt], 0, 0, 0);
    }

#pragma unroll
    for (int mt = 0; mt < 4; mt++)
#pragma unroll
        for (int nt = 0; nt < 4; nt++) {
            const int col = wv * 64 + nt * 16 + ln;
#pragma unroll
            for (int r = 0; r < 4; r++) {
                const int mm = m0 + mt * 16 + q * 4 + r;
                if (mm < VOCAB) EW[(long)mm * HID + col] = (_Float16)acc[mt][nt][r];
            }
        }
}

// ---------------------------------------------------------------------------
// Consumer R10: rows/block 8 -> 2 (grid 128), sigma exec-masked to ln<2,
// depth-2 MFMA chains. Model: wall = 512 x per-block chain; R5-R9 pinned the
// chain at ~1300 cyc invariant to LDS volume/conflicts/prefetch. The one term
// that scales with rows/block is the sigmoid trans work (rows x 256 x 2
// trans-lane-ops): R9 (16 rows, 2x trans) -> 2460; R6 (same 8 rows, 2x LDS)
// -> unchanged. rows=2 cuts per-block trans 4x; masking sigma+pack to the 2
// valid lanes (of 16) cuts active trans lanes 8x. Reads/wave (8 b128) and
// MFMA/wave (16) are row-invariant; 2 distinct read addrs x 8-way broadcast
// = conflict-free. 8 waves, 2/SIMD kept (R5: 1/SIMD exposes latency).
// ---------------------------------------------------------------------------
#define HSTR 272
#define NR   2
#define HBR  (NR * HSTR)
#define WSTR 513

__global__ __launch_bounds__(512, 2)
void k_recur(const float* __restrict__ Wh, const _Float16* __restrict__ EW,
             const int* __restrict__ words,
             const float* __restrict__ fcw, const float* __restrict__ fcb,
             float* __restrict__ out) {
    __shared__ __attribute__((aligned(16))) _Float16 hbuf[2 * HBR];
    __shared__ float red[128];
    __shared__ int   wlds[NR * WSTR];

    const int tid  = threadIdx.x;
    const int wv   = tid >> 6;        // 0..7, j-slice of 32
    const int lane = tid & 63;
    const int ln   = lane & 15;
    const int lnn  = ln & (NR - 1);   // broadcast source row
    const int q    = lane >> 4;
    const int b0   = blockIdx.x * NR;

    // Wh^T frags (scaled by -log2e): A'[m=j][k], j = wv*32 + mt*16 + ln
    f16x8 whf[8][2];
#pragma unroll
    for (int kc = 0; kc < 8; kc++) {
#pragma unroll
        for (int mt = 0; mt < 2; mt++) {
            const int j = wv * 32 + mt * 16 + ln;
            f16x8 u;
#pragma unroll
            for (int jj = 0; jj < 8; jj++)
                u[jj] = (_Float16)(Wh[(kc * 32 + q * 8 + jj) * HID + j] * NLOG2E);
            whf[kc][mt] = u;
        }
    }

    // Preload this block's word rows (coalesced) + zero both h buffers
    for (int i = tid; i < NR * S_LEN; i += 512) {
        const int r = i >> 9, c = i & 511;
        wlds[r * WSTR + c] = words[(b0 + r) * S_LEN + c];
    }
    for (int i = tid; i < 2 * HBR; i += 512) hbuf[i] = (_Float16)0.f;
    __syncthreads();

    const int jbase = wv * 32 + q * 4;   // + mt*16
    f16x4 abuf0[2], abuf1[2];
    {
        const int w0 = wlds[lnn * WSTR + 0];
        const int w1 = wlds[lnn * WSTR + 1];
        const _Float16* p0 = EW + ((long)w0 << 8) + jbase;
        const _Float16* p1 = EW + ((long)w1 << 8) + jbase;
#pragma unroll
        for (int mt = 0; mt < 2; mt++) abuf0[mt] = *(const f16x4*)(p0 + mt * 16);
#pragma unroll
        for (int mt = 0; mt < 2; mt++) abuf1[mt] = *(const f16x4*)(p1 + mt * 16);
    }

#define STEP(T, ABUF)                                                                   \
    {                                                                                   \
        const int tt = (T);                                                             \
        const _Float16* hr = hbuf + ((tt & 1) ? HBR : 0);                               \
        _Float16*       hw = hbuf + ((tt & 1) ? 0 : HBR);                               \
        f16x8 hf[8];                                                                    \
        _Pragma("unroll")                                                               \
        for (int kc = 0; kc < 8; kc++)                                                  \
            hf[kc] = *(const f16x8*)(hr + lnn * HSTR + kc * 32 + q * 8);                \
        f32x4 c0[2], c1[2], c2[2], c3[2];                                               \
        _Pragma("unroll")                                                               \
        for (int mt = 0; mt < 2; mt++) {            /* preact (f16->f32) as C-init */   \
            f16x4 av = ABUF[mt];                                                        \
            c0[mt] = f32x4{(float)av[0], (float)av[1], (float)av[2], (float)av[3]};     \
            c1[mt] = f32x4{0.f, 0.f, 0.f, 0.f};                                         \
            c2[mt] = f32x4{0.f, 0.f, 0.f, 0.f};                                         \
            c3[mt] = f32x4{0.f, 0.f, 0.f, 0.f};                                         \
        }                                                                               \
        const int t2 = (tt + 2 > 511) ? 511 : (tt + 2);                                 \
        const int wrow = wlds[lnn * WSTR + t2];                                         \
        const _Float16* rp = EW + ((long)wrow << 8) + jbase;                            \
        _Pragma("unroll")                                                               \
        for (int mt = 0; mt < 2; mt++) ABUF[mt] = *(const f16x4*)(rp + mt * 16);        \
        _Pragma("unroll")                                                               \
        for (int mt = 0; mt < 2; mt++) {            /* 8 chains, depth 2 */             \
            c0[mt] = __builtin_amdgcn_mfma_f32_16x16x32_f16(whf[0][mt], hf[0], c0[mt], 0, 0, 0); \
            c1[mt] = __builtin_amdgcn_mfma_f32_16x16x32_f16(whf[2][mt], hf[2], c1[mt], 0, 0, 0); \
            c2[mt] = __builtin_amdgcn_mfma_f32_16x16x32_f16(whf[4][mt], hf[4], c2[mt], 0, 0, 0); \
            c3[mt] = __builtin_amdgcn_mfma_f32_16x16x32_f16(whf[6][mt], hf[6], c3[mt], 0, 0, 0); \
            c0[mt] = __builtin_amdgcn_mfma_f32_16x16x32_f16(whf[1][mt], hf[1], c0[mt], 0, 0, 0); \
            c1[mt] = __builtin_amdgcn_mfma_f32_16x16x32_f16(whf[3][mt], hf[3], c1[mt], 0, 0, 0); \
            c2[mt] = __builtin_amdgcn_mfma_f32_16x16x32_f16(whf[5][mt], hf[5], c2[mt], 0, 0, 0); \
            c3[mt] = __builtin_amdgcn_mfma_f32_16x16x32_f16(whf[7][mt], hf[7], c3[mt], 0, 0, 0); \
        }                                                                               \
        if (ln < NR) {                              /* sigma only on valid lanes */     \
            _Pragma("unroll")                                                           \
            for (int mt = 0; mt < 2; mt++) {                                            \
                f32x4 s = (c0[mt] + c1[mt]) + (c2[mt] + c3[mt]);                        \
                float r0 = sigmoid_scaled(s[0]), r1 = sigmoid_scaled(s[1]);             \
                float r2 = sigmoid_scaled(s[2]), r3 = sigmoid_scaled(s[3]);             \
                union { fp16v2 h2[2]; f16x4 v4; } hp;                                   \
                hp.h2[0] = __builtin_amdgcn_cvt_pkrtz(r0, r1);                          \
                hp.h2[1] = __builtin_amdgcn_cvt_pkrtz(r2, r3);                          \
                *(f16x4*)(hw + ln * HSTR + wv * 32 + mt * 16 + q * 4) = hp.v4;          \
            }                                                                           \
        }                                                                               \
        block_sync_lds();                                                               \
    }

    for (int t = 0; t < S_LEN; t += 2) {
        STEP(t, abuf0);
        STEP(t + 1, abuf1);
    }
#undef STEP

    const _Float16* hf0 = hbuf;   // step 511 (odd) wrote buffer 0

    if (tid < 64 * NR) {   // hidden -> out[256 + (b0+row)*256 + j]
        const int row = tid >> 6, j0 = (tid & 63) * 4;
        float* dst = out + 256 + (long)(b0 + row) * HID + j0;
        f32x4 w;
#pragma unroll
        for (int r = 0; r < 4; r++) w[r] = (float)hf0[row * HSTR + j0 + r];
        *(f32x4*)dst = w;
    }

    if (tid < 64 * NR) {   // sig head: 64 partials x 4 elems per row
        const int row = tid >> 6, part = tid & 63;
        float s = 0.f;
#pragma unroll
        for (int jj = 0; jj < 4; jj++) {
            const int j = part * 4 + jj;
            s += (float)hf0[row * HSTR + j] * fcw[j];
        }
        red[row * 64 + part] = s;
    }
    __syncthreads();
    if (tid < NR) {
        float s = fcb[0];
#pragma unroll
        for (int p = 0; p < 64; p++) s += red[tid * 64 + p];
        s *= NLOG2E;
        out[b0 + tid] = sigmoid_scaled(s);
    }
}

extern "C" void kernel_launch(void* const* d_in, const int* in_sizes, int n_in,
                              void* d_out, int out_size, void* d_ws, size_t ws_size,
                              hipStream_t stream) {
    const int*   words = (const int*)d_in[0];
    const float* emb   = (const float*)d_in[1];
    const float* Wi    = (const float*)d_in[2];
    const float* Wh    = (const float*)d_in[3];
    const float* fcw   = (const float*)d_in[4];
    const float* fcb   = (const float*)d_in[5];
    _Float16* EW   = (_Float16*)d_ws;                          // 25.7 MB f16
    _Float16* WiT  = (_Float16*)((char*)d_ws + EW_BYTES);      // 160 KB f16
    float*    outp = (float*)d_out;

    hipLaunchKernelGGL(k_wprep, dim3(KPAD), dim3(256), 0, stream, Wi, WiT);
    hipLaunchKernelGGL(k_embwi, dim3(NPROD), dim3(256), 0, stream, emb, WiT, EW);
    hipLaunchKernelGGL(k_recur, dim3(BATCH / NR), dim3(512), 0, stream,
                       Wh, EW, words, fcw, fcb, outp);
}

// Round 12
// 397.062 us; speedup vs baseline: 1.6596x; 1.1060x over previous
//
#include <hip/hip_runtime.h>

#define S_LEN 512
#define BATCH 256
#define EMB   300
#define HID   256
#define VOCAB 50257
#define NPROD 786
#define NLOG2E -1.44269504089f

#define EW_BYTES 25731584ull            // 50257*256*2 (f16, pre-scaled by -log2e)
#define KPAD 320                        // WiT k-stride (300 padded to 320)

typedef __attribute__((ext_vector_type(8))) _Float16 f16x8;
typedef __attribute__((ext_vector_type(4))) _Float16 f16x4;
typedef __attribute__((ext_vector_type(2))) __fp16   fp16v2;
typedef __attribute__((ext_vector_type(4))) float    f32x4;

// Barrier waiting only lgkmcnt(0): LDS ordered, global loads stay in flight.
__device__ __forceinline__ void block_sync_lds() {
    asm volatile("" ::: "memory");
    __builtin_amdgcn_s_waitcnt(0xC07F);   // vmcnt=63, expcnt=7, lgkmcnt=0
    __builtin_amdgcn_s_barrier();
    asm volatile("" ::: "memory");
}

__device__ __forceinline__ float sigmoid_scaled(float xs) {   // xs = -log2e * x
    float e = __builtin_amdgcn_exp2f(xs);
    return __builtin_amdgcn_rcpf(1.0f + e);
}

// ---------------------------------------------------------------------------
// WiT[n][k] = f16( Wi[k][n] * -log2e ), k padded 300->320 with zeros.
// ---------------------------------------------------------------------------
__global__ __launch_bounds__(256)
void k_wprep(const float* __restrict__ Wi, _Float16* __restrict__ WiT) {
    const int k = blockIdx.x;      // 0..319
    const int n = threadIdx.x;     // 0..255
    _Float16 v = (_Float16)0.f;
    if (k < EMB) v = (_Float16)(Wi[k * HID + n] * NLOG2E);
    WiT[n * KPAD + k] = v;
}

// ---------------------------------------------------------------------------
// Producer: R4 structure; R11 adds a j-column PERMUTE at the EW write:
// within each 32-col group, col' = q*8 + mt*4 + r  (col = mt*16 + q*4 + r).
// This makes k_recur's per-step a-gather ONE f16x8 load (was 2x f16x4).
// ---------------------------------------------------------------------------
__global__ __launch_bounds__(256, 3)
void k_embwi(const float* __restrict__ emb, const _Float16* __restrict__ WiT,
             _Float16* __restrict__ EW) {
    const int tid  = threadIdx.x;
    const int wv   = tid >> 6;
    const int lane = tid & 63;
    const int ln   = lane & 15;
    const int q    = lane >> 4;
    const int m0   = blockIdx.x * 64;

    const _Float16* wbn[4];
#pragma unroll
    for (int nt = 0; nt < 4; nt++)
        wbn[nt] = WiT + (wv * 64 + nt * 16 + ln) * KPAD + q * 8;

    const float* arow[4];
#pragma unroll
    for (int mt = 0; mt < 4; mt++) {
        int row = m0 + mt * 16 + ln; if (row >= VOCAB) row = VOCAB - 1;
        arow[mt] = emb + (long)row * EMB + q * 8;
    }

    auto load_af = [&](int kc, int mt) -> f16x8 {
        const float* p = arow[mt] + kc * 32;
        f16x8 v;
        if (kc < 9 || q == 0) {
            f32x4 a = *(const f32x4*)p;
            f32x4 b = *(const f32x4*)(p + 4);
#pragma unroll
            for (int r = 0; r < 4; r++) { v[r] = (_Float16)a[r]; v[4 + r] = (_Float16)b[r]; }
        } else if (q == 1) {
            f32x4 a = *(const f32x4*)p;
#pragma unroll
            for (int r = 0; r < 4; r++) { v[r] = (_Float16)a[r]; v[4 + r] = (_Float16)0.f; }
        } else {
#pragma unroll
            for (int r = 0; r < 8; r++) v[r] = (_Float16)0.f;
        }
        return v;
    };

    f32x4 acc[4][4];
#pragma unroll
    for (int mt = 0; mt < 4; mt++)
#pragma unroll
        for (int nt = 0; nt < 4; nt++)
            acc[mt][nt] = f32x4{0.f, 0.f, 0.f, 0.f};

#pragma unroll
    for (int kc = 0; kc < 10; kc++) {
        f16x8 af[4], bf[4];
#pragma unroll
        for (int mt = 0; mt < 4; mt++) af[mt] = load_af(kc, mt);
#pragma unroll
        for (int nt = 0; nt < 4; nt++) bf[nt] = *(const f16x8*)(wbn[nt] + kc * 32);
#pragma unroll
        for (int mt = 0; mt < 4; mt++)
#pragma unroll
            for (int nt = 0; nt < 4; nt++)
                acc[mt][nt] = __builtin_amdgcn_mfma_f32_16x16x32_f16(
                    af[mt], bf[nt], acc[mt][nt], 0, 0, 0);
    }

#pragma unroll
    for (int mt = 0; mt < 4; mt++)
#pragma unroll
        for (int nt = 0; nt < 4; nt++) {
            const int col = wv * 64 + nt * 16 + ln;
            // permute within 32-group: low = mtb*16 + qb*4 + rb -> qb*8 + mtb*4 + rb
            const int low = col & 31;
            const int colp = (col & ~31) | (((low >> 2) & 3) << 3) | ((low >> 4) << 2) | (low & 3);
#pragma unroll
            for (int r = 0; r < 4; r++) {
                const int mm = m0 + mt * 16 + q * 4 + r;
                if (mm < VOCAB) EW[(long)mm * HID + colp] = (_Float16)acc[mt][nt][r];
            }
        }
}

// ---------------------------------------------------------------------------
// Consumer R11: R8 base (8 waves, HSTR 272) + instruction diet. R10 counters
// (active-CU VALUBusy ~45%, MfmaUtil ~38%) show the step is ISSUE-bound:
// MFMA 32/SIMD x ~16cyc = 512, VALU ~600, LDS ~200 => ~1300 = measured chain.
// Cuts: (1) sigma-split -- lanes ln and ln+8 hold IDENTICAL accs (hf dep on
// lnn only; C col = batch slot), so ln<8 sigmoids mt0, ln>=8 mt1: 8->4
// sigmoids/lane, one ds_write per lane (was 2 on half lanes). (2) abuf = one
// f16x8 via EW permute. (3) depth-8 dual chains, no adds. (4) clampless main
// loop, peeled tail.
// ---------------------------------------------------------------------------
#define HSTR 272
#define HB8  (8 * HSTR)
#define WSTR 513

__global__ __launch_bounds__(512, 2)
void k_recur(const float* __restrict__ Wh, const _Float16* __restrict__ EW,
             const int* __restrict__ words,
             const float* __restrict__ fcw, const float* __restrict__ fcb,
             float* __restrict__ out) {
    __shared__ __attribute__((aligned(16))) _Float16 hbuf[2 * HB8];
    __shared__ float red[512];
    __shared__ int   wlds[8 * WSTR];

    const int tid  = threadIdx.x;
    const int wv   = tid >> 6;        // 0..7, j-slice of 32
    const int lane = tid & 63;
    const int ln   = lane & 15;
    const int lnn  = ln & 7;          // broadcast source row
    const int q    = lane >> 4;
    const int b0   = blockIdx.x * 8;
    const int half = (ln >= 8) ? 1 : 0;   // sigma-split: which mt this lane owns

    // Wh^T frags (scaled by -log2e): A'[m=j][k], j = wv*32 + mt*16 + ln
    f16x8 whf[8][2];
#pragma unroll
    for (int kc = 0; kc < 8; kc++) {
#pragma unroll
        for (int mt = 0; mt < 2; mt++) {
            const int j = wv * 32 + mt * 16 + ln;
            f16x8 u;
#pragma unroll
            for (int jj = 0; jj < 8; jj++)
                u[jj] = (_Float16)(Wh[(kc * 32 + q * 8 + jj) * HID + j] * NLOG2E);
            whf[kc][mt] = u;
        }
    }

    // Preload this block's word rows (coalesced) + zero both h buffers
#pragma unroll
    for (int i = tid; i < 8 * S_LEN; i += 512) {
        const int r = i >> 9, c = i & 511;
        wlds[r * WSTR + c] = words[(b0 + r) * S_LEN + c];
    }
    for (int i = tid; i < 2 * HB8; i += 512) hbuf[i] = (_Float16)0.f;
    __syncthreads();

    const int jb8 = wv * 32 + q * 8;     // permuted EW offset: one f16x8
    f16x8 abuf0, abuf1;
    {
        const int w0 = wlds[lnn * WSTR + 0];
        const int w1 = wlds[lnn * WSTR + 1];
        abuf0 = *(const f16x8*)(EW + ((long)w0 << 8) + jb8);
        abuf1 = *(const f16x8*)(EW + ((long)w1 << 8) + jb8);
    }

#define STEP(T, ABUF, T2)                                                               \
    {                                                                                   \
        const int tt = (T);                                                             \
        const _Float16* hr = hbuf + ((tt & 1) ? HB8 : 0);                               \
        _Float16*       hw = hbuf + ((tt & 1) ? 0 : HB8);                               \
        f16x8 hf[8];                                                                    \
        _Pragma("unroll")                                                               \
        for (int kc = 0; kc < 8; kc++)                                                  \
            hf[kc] = *(const f16x8*)(hr + lnn * HSTR + kc * 32 + q * 8);                \
        f32x4 acc0, acc1;                            /* preact (f16->f32) as C-init */  \
        acc0 = f32x4{(float)ABUF[0], (float)ABUF[1], (float)ABUF[2], (float)ABUF[3]};   \
        acc1 = f32x4{(float)ABUF[4], (float)ABUF[5], (float)ABUF[6], (float)ABUF[7]};   \
        const int wrow = wlds[lnn * WSTR + (T2)];                                       \
        ABUF = *(const f16x8*)(EW + ((long)wrow << 8) + jb8);                           \
        _Pragma("unroll")                                                               \
        for (int r = 0; r < 8; r++) {               /* 2 chains, depth 8 */             \
            acc0 = __builtin_amdgcn_mfma_f32_16x16x32_f16(whf[r][0], hf[r], acc0, 0, 0, 0); \
            acc1 = __builtin_amdgcn_mfma_f32_16x16x32_f16(whf[r][1], hf[r], acc1, 0, 0, 0); \
        }                                                                               \
        {   /* sigma-split: ln<8 -> mt0, ln>=8 -> mt1 (accs duplicated in n) */         \
            float s0 = half ? acc1[0] : acc0[0];                                        \
            float s1 = half ? acc1[1] : acc0[1];                                        \
            float s2 = half ? acc1[2] : acc0[2];                                        \
            float s3 = half ? acc1[3] : acc0[3];                                        \
            float r0 = sigmoid_scaled(s0), r1 = sigmoid_scaled(s1);                     \
            float r2 = sigmoid_scaled(s2), r3 = sigmoid_scaled(s3);                     \
            union { fp16v2 h2[2]; f16x4 v4; } hp;                                       \
            hp.h2[0] = __builtin_amdgcn_cvt_pkrtz(r0, r1);                              \
            hp.h2[1] = __builtin_amdgcn_cvt_pkrtz(r2, r3);                              \
            *(f16x4*)(hw + lnn * HSTR + wv * 32 + half * 16 + q * 4) = hp.v4;           \
        }                                                                               \
        block_sync_lds();                                                               \
    }

    for (int t = 0; t < 510; t += 2) {
        STEP(t, abuf0, tt + 2);
        STEP(t + 1, abuf1, tt + 2);
    }
    STEP(510, abuf0, 511);
    STEP(511, abuf1, 511);
#undef STEP

    const _Float16* hf0 = hbuf;   // step 511 (odd) wrote buffer 0

    {   // hidden -> out[256 + (b0+row)*256 + j], rows 0..7, 4 f32 per thread
        const int row = tid >> 6, j0 = (tid & 63) * 4;
        float* dst = out + 256 + (long)(b0 + row) * HID + j0;
        f32x4 w;
#pragma unroll
        for (int r = 0; r < 4; r++) w[r] = (float)hf0[row * HSTR + j0 + r];
        *(f32x4*)dst = w;
    }

    {   // sig head: 64 partials x 4 elems per row
        const int row = tid >> 6, part = tid & 63;
        float s = 0.f;
#pragma unroll
        for (int jj = 0; jj < 4; jj++) {
            const int j = part * 4 + jj;
            s += (float)hf0[row * HSTR + j] * fcw[j];
        }
        red[row * 64 + part] = s;
    }
    __syncthreads();
    if (tid < 8) {
        float s = fcb[0];
#pragma unroll
        for (int p = 0; p < 64; p++) s += red[tid * 64 + p];
        s *= NLOG2E;
        out[b0 + tid] = sigmoid_scaled(s);
    }
}

extern "C" void kernel_launch(void* const* d_in, const int* in_sizes, int n_in,
                              void* d_out, int out_size, void* d_ws, size_t ws_size,
                              hipStream_t stream) {
    const int*   words = (const int*)d_in[0];
    const float* emb   = (const float*)d_in[1];
    const float* Wi    = (const float*)d_in[2];
    const float* Wh    = (const float*)d_in[3];
    const float* fcw   = (const float*)d_in[4];
    const float* fcb   = (const float*)d_in[5];
    _Float16* EW   = (_Float16*)d_ws;                          // 25.7 MB f16
    _Float16* WiT  = (_Float16*)((char*)d_ws + EW_BYTES);      // 160 KB f16
    float*    outp = (float*)d_out;

    hipLaunchKernelGGL(k_wprep, dim3(KPAD), dim3(256), 0, stream, Wi, WiT);
    hipLaunchKernelGGL(k_embwi, dim3(NPROD), dim3(256), 0, stream, emb, WiT, EW);
    hipLaunchKernelGGL(k_recur, dim3(BATCH / 8), dim3(512), 0, stream,
                       Wh, EW, words, fcw, fcb, outp);
}

// Round 16
// 383.694 us; speedup vs baseline: 1.7174x; 1.0348x over previous
//
#include <hip/hip_runtime.h>

#define S_LEN 512
#define BATCH 256
#define EMB   300
#define HID   256
#define VOCAB 50257
#define NPROD 786
#define NLOG2E -1.44269504089f

#define EW_BYTES 25731584ull            // 50257*256*2 (f16, pre-scaled by -log2e)
#define KPAD 320                        // WiT k-stride (300 padded to 320)

typedef __attribute__((ext_vector_type(8))) _Float16 f16x8;
typedef __attribute__((ext_vector_type(4))) _Float16 f16x4;
typedef __attribute__((ext_vector_type(2))) __fp16   fp16v2;
typedef __attribute__((ext_vector_type(4))) float    f32x4;

// Barrier waiting only lgkmcnt(0): LDS ordered, global loads stay in flight.
__device__ __forceinline__ void block_sync_lds() {
    asm volatile("" ::: "memory");
    __builtin_amdgcn_s_waitcnt(0xC07F);   // vmcnt=63, expcnt=7, lgkmcnt=0
    __builtin_amdgcn_s_barrier();
    asm volatile("" ::: "memory");
}

__device__ __forceinline__ float sigmoid_scaled(float xs) {   // xs = -log2e * x
    float e = __builtin_amdgcn_exp2f(xs);
    return __builtin_amdgcn_rcpf(1.0f + e);
}

// ---------------------------------------------------------------------------
// WiT[n][k] = f16( Wi[k][n] * -log2e ), k padded 300->320 with zeros.
// ---------------------------------------------------------------------------
__global__ __launch_bounds__(256)
void k_wprep(const float* __restrict__ Wi, _Float16* __restrict__ WiT) {
    const int k = blockIdx.x;      // 0..319
    const int n = threadIdx.x;     // 0..255
    _Float16 v = (_Float16)0.f;
    if (k < EMB) v = (_Float16)(Wi[k * HID + n] * NLOG2E);
    WiT[n * KPAD + k] = v;
}

// ---------------------------------------------------------------------------
// Producer R13: LDS-staged COALESCED emb reads. All prior k_embwi variants
// (R0/R3/R4, all ~equal) shared uncoalesced 32-B gathers from 16 rows x
// 1200-B stride -- the one untested variable for the stable ~137us residual.
// Phase 1: linear f32x4 loads (consecutive tid -> consecutive addr), f16
// convert, store LDS tile [64][ASTR=328] (bank phase ln*4 mod 32 -> 2-way,
// free). Phase 2: MFMA with af from ds_read_b128, bf from WiT (L2).
// EW col-permute (R11) retained: col' = q*8+mt*4+r within each 32-group.
// ---------------------------------------------------------------------------
#define ASTR 328

__global__ __launch_bounds__(256, 2)
void k_embwi(const float* __restrict__ emb, const _Float16* __restrict__ WiT,
             _Float16* __restrict__ EW) {
    __shared__ __attribute__((aligned(16))) _Float16 atile[64 * ASTR];

    const int tid  = threadIdx.x;
    const int wv   = tid >> 6;
    const int lane = tid & 63;
    const int ln   = lane & 15;
    const int q    = lane >> 4;
    const int m0   = blockIdx.x * 64;

    // ---- Phase 1: coalesced stage. 64 rows x 75 f32x4 chunks = 4800.
    for (int i = tid; i < 64 * 75; i += 256) {
        const int r  = i / 75;
        const int c4 = i % 75;
        int rg = m0 + r; if (rg >= VOCAB) rg = VOCAB - 1;
        f32x4 v = *(const f32x4*)(emb + (long)rg * EMB + c4 * 4);
        f16x4 h;
#pragma unroll
        for (int e = 0; e < 4; e++) h[e] = (_Float16)v[e];
        *(f16x4*)(atile + r * ASTR + c4 * 4) = h;
    }
    // zero pad cols 300..319 (read range of kc=9; WiT also zero there)
    for (int i = tid; i < 64 * 20; i += 256) {
        const int r = i / 20, c = 300 + i % 20;
        atile[r * ASTR + c] = (_Float16)0.f;
    }
    __syncthreads();

    // ---- Phase 2: MFMA from LDS(af) + WiT(bf).
    const _Float16* wbn[4];
#pragma unroll
    for (int nt = 0; nt < 4; nt++)
        wbn[nt] = WiT + (wv * 64 + nt * 16 + ln) * KPAD + q * 8;

    f32x4 acc[4][4];
#pragma unroll
    for (int mt = 0; mt < 4; mt++)
#pragma unroll
        for (int nt = 0; nt < 4; nt++)
            acc[mt][nt] = f32x4{0.f, 0.f, 0.f, 0.f};

#pragma unroll
    for (int kc = 0; kc < 10; kc++) {
        f16x8 af[4], bf[4];
#pragma unroll
        for (int mt = 0; mt < 4; mt++)
            af[mt] = *(const f16x8*)(atile + (mt * 16 + ln) * ASTR + kc * 32 + q * 8);
#pragma unroll
        for (int nt = 0; nt < 4; nt++) bf[nt] = *(const f16x8*)(wbn[nt] + kc * 32);
#pragma unroll
        for (int mt = 0; mt < 4; mt++)
#pragma unroll
            for (int nt = 0; nt < 4; nt++)
                acc[mt][nt] = __builtin_amdgcn_mfma_f32_16x16x32_f16(
                    af[mt], bf[nt], acc[mt][nt], 0, 0, 0);
    }

#pragma unroll
    for (int mt = 0; mt < 4; mt++)
#pragma unroll
        for (int nt = 0; nt < 4; nt++) {
            const int col = wv * 64 + nt * 16 + ln;
            // permute within 32-group: low = mtb*16 + qb*4 + rb -> qb*8 + mtb*4 + rb
            const int low = col & 31;
            const int colp = (col & ~31) | (((low >> 2) & 3) << 3) | ((low >> 4) << 2) | (low & 3);
#pragma unroll
            for (int r = 0; r < 4; r++) {
                const int mm = m0 + mt * 16 + q * 4 + r;
                if (mm < VOCAB) EW[(long)mm * HID + colp] = (_Float16)acc[mt][nt][r];
            }
        }
}

// ---------------------------------------------------------------------------
// Consumer: BYTE-IDENTICAL to R12 (259.6 us measured) for a clean A/B.
// ---------------------------------------------------------------------------
#define HSTR 272
#define HB8  (8 * HSTR)
#define WSTR 513

__global__ __launch_bounds__(512, 2)
void k_recur(const float* __restrict__ Wh, const _Float16* __restrict__ EW,
             const int* __restrict__ words,
             const float* __restrict__ fcw, const float* __restrict__ fcb,
             float* __restrict__ out) {
    __shared__ __attribute__((aligned(16))) _Float16 hbuf[2 * HB8];
    __shared__ float red[512];
    __shared__ int   wlds[8 * WSTR];

    const int tid  = threadIdx.x;
    const int wv   = tid >> 6;        // 0..7, j-slice of 32
    const int lane = tid & 63;
    const int ln   = lane & 15;
    const int lnn  = ln & 7;          // broadcast source row
    const int q    = lane >> 4;
    const int b0   = blockIdx.x * 8;
    const int half = (ln >= 8) ? 1 : 0;   // sigma-split: which mt this lane owns

    // Wh^T frags (scaled by -log2e): A'[m=j][k], j = wv*32 + mt*16 + ln
    f16x8 whf[8][2];
#pragma unroll
    for (int kc = 0; kc < 8; kc++) {
#pragma unroll
        for (int mt = 0; mt < 2; mt++) {
            const int j = wv * 32 + mt * 16 + ln;
            f16x8 u;
#pragma unroll
            for (int jj = 0; jj < 8; jj++)
                u[jj] = (_Float16)(Wh[(kc * 32 + q * 8 + jj) * HID + j] * NLOG2E);
            whf[kc][mt] = u;
        }
    }

    // Preload this block's word rows (coalesced) + zero both h buffers
#pragma unroll
    for (int i = tid; i < 8 * S_LEN; i += 512) {
        const int r = i >> 9, c = i & 511;
        wlds[r * WSTR + c] = words[(b0 + r) * S_LEN + c];
    }
    for (int i = tid; i < 2 * HB8; i += 512) hbuf[i] = (_Float16)0.f;
    __syncthreads();

    const int jb8 = wv * 32 + q * 8;     // permuted EW offset: one f16x8
    f16x8 abuf0, abuf1;
    {
        const int w0 = wlds[lnn * WSTR + 0];
        const int w1 = wlds[lnn * WSTR + 1];
        abuf0 = *(const f16x8*)(EW + ((long)w0 << 8) + jb8);
        abuf1 = *(const f16x8*)(EW + ((long)w1 << 8) + jb8);
    }

#define STEP(T, ABUF, T2)                                                               \
    {                                                                                   \
        const int tt = (T);                                                             \
        const _Float16* hr = hbuf + ((tt & 1) ? HB8 : 0);                               \
        _Float16*       hw = hbuf + ((tt & 1) ? 0 : HB8);                               \
        f16x8 hf[8];                                                                    \
        _Pragma("unroll")                                                               \
        for (int kc = 0; kc < 8; kc++)                                                  \
            hf[kc] = *(const f16x8*)(hr + lnn * HSTR + kc * 32 + q * 8);                \
        f32x4 acc0, acc1;                            /* preact (f16->f32) as C-init */  \
        acc0 = f32x4{(float)ABUF[0], (float)ABUF[1], (float)ABUF[2], (float)ABUF[3]};   \
        acc1 = f32x4{(float)ABUF[4], (float)ABUF[5], (float)ABUF[6], (float)ABUF[7]};   \
        const int wrow = wlds[lnn * WSTR + (T2)];                                       \
        ABUF = *(const f16x8*)(EW + ((long)wrow << 8) + jb8);                           \
        _Pragma("unroll")                                                               \
        for (int r = 0; r < 8; r++) {               /* 2 chains, depth 8 */             \
            acc0 = __builtin_amdgcn_mfma_f32_16x16x32_f16(whf[r][0], hf[r], acc0, 0, 0, 0); \
            acc1 = __builtin_amdgcn_mfma_f32_16x16x32_f16(whf[r][1], hf[r], acc1, 0, 0, 0); \
        }                                                                               \
        {   /* sigma-split: ln<8 -> mt0, ln>=8 -> mt1 (accs duplicated in n) */         \
            float s0 = half ? acc1[0] : acc0[0];                                        \
            float s1 = half ? acc1[1] : acc0[1];                                        \
            float s2 = half ? acc1[2] : acc0[2];                                        \
            float s3 = half ? acc1[3] : acc0[3];                                        \
            float r0 = sigmoid_scaled(s0), r1 = sigmoid_scaled(s1);                     \
            float r2 = sigmoid_scaled(s2), r3 = sigmoid_scaled(s3);                     \
            union { fp16v2 h2[2]; f16x4 v4; } hp;                                       \
            hp.h2[0] = __builtin_amdgcn_cvt_pkrtz(r0, r1);                              \
            hp.h2[1] = __builtin_amdgcn_cvt_pkrtz(r2, r3);                              \
            *(f16x4*)(hw + lnn * HSTR + wv * 32 + half * 16 + q * 4) = hp.v4;           \
        }                                                                               \
        block_sync_lds();                                                               \
    }

    for (int t = 0; t < 510; t += 2) {
        STEP(t, abuf0, tt + 2);
        STEP(t + 1, abuf1, tt + 2);
    }
    STEP(510, abuf0, 511);
    STEP(511, abuf1, 511);
#undef STEP

    const _Float16* hf0 = hbuf;   // step 511 (odd) wrote buffer 0

    {   // hidden -> out[256 + (b0+row)*256 + j], rows 0..7, 4 f32 per thread
        const int row = tid >> 6, j0 = (tid & 63) * 4;
        float* dst = out + 256 + (long)(b0 + row) * HID + j0;
        f32x4 w;
#pragma unroll
        for (int r = 0; r < 4; r++) w[r] = (float)hf0[row * HSTR + j0 + r];
        *(f32x4*)dst = w;
    }

    {   // sig head: 64 partials x 4 elems per row
        const int row = tid >> 6, part = tid & 63;
        float s = 0.f;
#pragma unroll
        for (int jj = 0; jj < 4; jj++) {
            const int j = part * 4 + jj;
            s += (float)hf0[row * HSTR + j] * fcw[j];
        }
        red[row * 64 + part] = s;
    }
    __syncthreads();
    if (tid < 8) {
        float s = fcb[0];
#pragma unroll
        for (int p = 0; p < 64; p++) s += red[tid * 64 + p];
        s *= NLOG2E;
        out[b0 + tid] = sigmoid_scaled(s);
    }
}

extern "C" void kernel_launch(void* const* d_in, const int* in_sizes, int n_in,
                              void* d_out, int out_size, void* d_ws, size_t ws_size,
                              hipStream_t stream) {
    const int*   words = (const int*)d_in[0];
    const float* emb   = (const float*)d_in[1];
    const float* Wi    = (const float*)d_in[2];
    const float* Wh    = (const float*)d_in[3];
    const float* fcw   = (const float*)d_in[4];
    const float* fcb   = (const float*)d_in[5];
    _Float16* EW   = (_Float16*)d_ws;                          // 25.7 MB f16
    _Float16* WiT  = (_Float16*)((char*)d_ws + EW_BYTES);      // 160 KB f16
    float*    outp = (float*)d_out;

    hipLaunchKernelGGL(k_wprep, dim3(KPAD), dim3(256), 0, stream, Wi, WiT);
    hipLaunchKernelGGL(k_embwi, dim3(NPROD), dim3(256), 0, stream, emb, WiT, EW);
    hipLaunchKernelGGL(k_recur, dim3(BATCH / 8), dim3(512), 0, stream,
                       Wh, EW, words, fcw, fcb, outp);
}